// Round 8
// baseline (65.540 us; speedup 1.0000x reference)
//
#include <hip/hip_runtime.h>

// MultiHeadDense: out[b] = x[b] @ W[idx[b]] + bias[idx[b]]
// B=4096, D=1024, F=1024, H=8. fp32 in/out; bf16 MFMA internally.
// Round 8: load path caps ~26-29 GB/s/CU at <=2 resident blocks/CU; m97
// measured 50 GB/s/CU with 3 resident blocks (independent barriers overlap).
// -> K-split-2 on the proven r6 GEMM: 1024 working blocks, 3 resident/CU
//    (48KB LDS cap), 12 waves/CU. Epilogue = unsafeAtomicAdd onto out
//    pre-initialized with bias (fused into k_gather). Traffic unchanged.

typedef __attribute__((ext_vector_type(8))) short bf16x8;
typedef __attribute__((ext_vector_type(4))) float f32x4;

#define WAITV(N) asm volatile("s_waitcnt vmcnt(" #N ")" ::: "memory")

static __device__ __forceinline__ unsigned short f2bf(float f) {
  union { float f; unsigned int u; } c; c.f = f;
  unsigned int u = c.u;
  return (unsigned short)((u + 0x7fffu + ((u >> 16) & 1u)) >> 16);
}

static __device__ __forceinline__ void gload16(const void* g, void* s) {
  __builtin_amdgcn_global_load_lds(
      (const __attribute__((address_space(1))) void*)g,
      (__attribute__((address_space(3))) void*)s, 16, 0, 0);
}

// Kernel 1 (fused): blocks 0..2047 transpose+convert W [H][D][F] fp32 ->
// Wt [H][F][D-swizzled] bf16 (chunk c of each 64-K group stored at c^(frow&7)).
// Block 2048: counting-sort scan of idx -> rows[] + cnt[] + base8[] (8-aligned
// head bases; gap slots zero-filled). No atomics anywhere.
__global__ __launch_bounds__(256) void k_prep(
    const float* __restrict__ W, const int* __restrict__ idx,
    unsigned short* __restrict__ Wt, int* __restrict__ cnt,
    int* __restrict__ base8, int* __restrict__ rows) {
  const int bid = blockIdx.x;
  const int t = threadIdx.x;

  if (bid >= 2048) {
    __shared__ int sc[256][8];
    int myi[16];
#pragma unroll
    for (int i = 0; i < 4; ++i) {
      const int4 v = *(const int4*)(idx + t * 16 + i * 4);
      myi[i * 4 + 0] = v.x; myi[i * 4 + 1] = v.y;
      myi[i * 4 + 2] = v.z; myi[i * 4 + 3] = v.w;
    }
    int c[8];
#pragma unroll
    for (int h = 0; h < 8; ++h) c[h] = 0;
#pragma unroll
    for (int e = 0; e < 16; ++e)
#pragma unroll
      for (int h = 0; h < 8; ++h) c[h] += (myi[e] == h) ? 1 : 0;

    int val[8];
#pragma unroll
    for (int h = 0; h < 8; ++h) { val[h] = c[h]; sc[t][h] = c[h]; }
    __syncthreads();
    for (int off = 1; off < 256; off <<= 1) {
      int nb[8];
#pragma unroll
      for (int h = 0; h < 8; ++h) nb[h] = (t >= off) ? sc[t - off][h] : 0;
      __syncthreads();
#pragma unroll
      for (int h = 0; h < 8; ++h) { val[h] += nb[h]; sc[t][h] = val[h]; }
      __syncthreads();
    }
    int tot[8], excl[8];
#pragma unroll
    for (int h = 0; h < 8; ++h) tot[h] = sc[255][h];
#pragma unroll
    for (int h = 0; h < 8; ++h) excl[h] = val[h] - c[h];
    int bases[9];
    bases[0] = 0;
#pragma unroll
    for (int h = 0; h < 7; ++h) bases[h + 1] = (bases[h] + tot[h] + 7) & ~7;
    bases[8] = bases[7] + tot[7];
#pragma unroll
    for (int h = 0; h < 8; ++h) {
      int pos = bases[h] + excl[h];
#pragma unroll
      for (int e = 0; e < 16; ++e) {
        if (myi[e] == h) { rows[pos] = t * 16 + e; ++pos; }
      }
    }
    if (t < 56) {
      const int hh = t >> 3, j = t & 7;
      const int pos = bases[hh] + tot[hh] + j;
      if (pos < bases[hh + 1]) rows[pos] = 0;
    }
    if (t < 128) {
      const int pos = bases[8] + t;
      if (pos < 4160) rows[pos] = 0;
    }
    if (t < 8) cnt[t] = tot[t];
    if (t == 0) {
#pragma unroll
      for (int h = 0; h < 9; ++h) base8[h] = bases[h];
    }
    return;
  }

  // ---- transpose block: 64x64 tile of head h ----
  __shared__ unsigned short tile[64][68];
  const int h = bid >> 8;
  const int rem = bid & 255;
  const int d0 = (rem >> 4) << 6;
  const int f0 = (rem & 15) << 6;
  const int c4 = (t & 15) * 4;
  const int r0 = t >> 4;
#pragma unroll
  for (int i = 0; i < 4; ++i) {
    const int r = r0 + i * 16;
    const float4 v = *(const float4*)(W + (size_t)(h * 1024 + d0 + r) * 1024 + f0 + c4);
    tile[r][c4 + 0] = f2bf(v.x);
    tile[r][c4 + 1] = f2bf(v.y);
    tile[r][c4 + 2] = f2bf(v.z);
    tile[r][c4 + 3] = f2bf(v.w);
  }
  __syncthreads();
  const int chunk = c4 >> 3;
  const int half = (c4 >> 2) & 1;
#pragma unroll
  for (int i = 0; i < 4; ++i) {
    const int fr = r0 + i * 16;
    const int frow = f0 + fr;
    ushort4 o;
    o.x = tile[c4 + 0][fr];
    o.y = tile[c4 + 1][fr];
    o.z = tile[c4 + 2][fr];
    o.w = tile[c4 + 3][fr];
    const int cS = chunk ^ (frow & 7);  // baked LDS swizzle
    *(ushort4*)((char*)Wt + (size_t)(h * 1024 + frow) * 2048 +
                (d0 << 1) + (cS << 4) + (half << 3)) = o;
  }
}

// Kernel 2: permuted gather-copy X row rows[slot] -> Ap[slot] (bf16,
// chunk-swizzled by slot&7), AND pre-init out[b] = bias[idx[b]] (the GEMM
// epilogue atomically accumulates onto this). Pad slots re-init row 0
// idempotently (same value) - harmless.
__global__ __launch_bounds__(256) void k_gather(
    const float* __restrict__ X, const int* __restrict__ idx,
    const int* __restrict__ rows, unsigned short* __restrict__ Ap,
    const float* __restrict__ bias, float* __restrict__ out) {
  const int slot = blockIdx.x;
  const int b = rows[slot];
  const int t = threadIdx.x;
  const float4 v = *(const float4*)(X + (size_t)b * 1024 + t * 4);
  ushort4 o;
  o.x = f2bf(v.x); o.y = f2bf(v.y); o.z = f2bf(v.z); o.w = f2bf(v.w);
  const int g = t >> 4;
  const int cS = ((t >> 1) & 7) ^ (slot & 7);
  *(ushort4*)((char*)Ap + (size_t)slot * 2048 + (g << 7) + (cS << 4) +
              ((t & 1) << 3)) = o;
  // bias pre-init of the output row
  const int h = idx[b];
  const float4 bv = *(const float4*)(bias + h * 1024 + t * 4);
  *(float4*)(out + (size_t)b * 1024 + t * 4) = bv;
}

// Kernel 3: grouped GEMM, 128Mx64N tile, BK=64, K-split-2 (each block does
// K=512, 8 steps). 4 waves (2x2, each 64x32, 4x2 frag accs). dbuf 48KB LDS
// -> 3 resident blocks/CU = 12 waves/CU (m97's measured-50GB/s/CU config).
// Linear staging (swizzle baked in Ap/Wt), counted vmcnt(6) (never 0
// mid-loop). h=blk&7 -> XCD affinity. Epilogue: unsafeAtomicAdd onto
// bias-pre-initialized out.
__global__ __launch_bounds__(256) void k_gemm(
    const unsigned short* __restrict__ Ap, const unsigned short* __restrict__ Wt,
    const int* __restrict__ rows, const int* __restrict__ cnt,
    const int* __restrict__ base8,
    float* __restrict__ out) {
  __shared__ __align__(16) unsigned short As[2][128 * 64];
  __shared__ __align__(16) unsigned short Bs[2][64 * 64];

  const int blk = blockIdx.x;
  const int h = blk & 7;           // head -> XCD affinity
  const int nt = (blk >> 3) & 15;  // 16 n-tiles of 64
  const int ks = (blk >> 7) & 1;   // K-split half
  const int mt = blk >> 8;         // up to 16 m-tiles of 128

  const int cnt_h = cnt[h];
  const int basep = base8[h];
  const int m0 = mt * 128;
  if (m0 >= cnt_h) return;
  const int n0 = nt * 64;
  const int kb = ks * 512;         // this block's K base (elements)

  const int t = threadIdx.x;
  const int lane = t & 63;
  const int wave = t >> 6;
  const int wr = wave >> 1, wc = wave & 1;  // wave tile: 64 rows x 32 cols

  // Linear per-row staging source pointers (A clamped vs Ap's 4224 rows).
  const int srow = t >> 3;                 // 0..31
  const int scol = (t & 7) << 4;           // linear 16B chunk
  const char* aRow[4];
  const char* bRow[2];
#pragma unroll
  for (int r = 0; r < 4; ++r) {
    int ar = basep + m0 + r * 32 + srow;
    ar = ar < 4223 ? ar : 4223;
    aRow[r] = (const char*)Ap + (size_t)ar * 2048 + scol;
  }
#pragma unroll
  for (int r = 0; r < 2; ++r)
    bRow[r] = (const char*)Wt + (size_t)(h * 1024 + n0 + r * 32 + srow) * 2048 + scol;

  f32x4 acc[4][2];
#pragma unroll
  for (int m = 0; m < 4; ++m)
#pragma unroll
    for (int n = 0; n < 2; ++n)
      acc[m][n] = (f32x4){0.f, 0.f, 0.f, 0.f};

  auto stage = [&](int s, int k0) {  // 6 gload16 per thread (4 A + 2 B)
#pragma unroll
    for (int r = 0; r < 4; ++r)
      gload16(aRow[r] + k0 * 2, (char*)(&As[s][0]) + r * 4096 + t * 16);
#pragma unroll
    for (int r = 0; r < 2; ++r)
      gload16(bRow[r] + k0 * 2, (char*)(&Bs[s][0]) + r * 4096 + t * 16);
  };

  const int swz = (lane & 7) << 4;
  const int ra = (wr * 64 + (lane & 15)) * 128;  // A frag byte base
  const int rb = (wc * 32 + (lane & 15)) * 128;  // B frag byte base
  const int kc = (lane >> 4) << 4;

  auto compute = [&](int s) {
    const char* ab = (const char*)(&As[s][0]);
    const char* bb = (const char*)(&Bs[s][0]);
#pragma unroll
    for (int ksub = 0; ksub < 2; ++ksub) {
      const int co = ((ksub * 64) + kc) ^ swz;
      bf16x8 af[4], bfr[2];
#pragma unroll
      for (int a = 0; a < 4; ++a)
        af[a] = *(const bf16x8*)(ab + ra + a * 2048 + co);
#pragma unroll
      for (int b = 0; b < 2; ++b)
        bfr[b] = *(const bf16x8*)(bb + rb + b * 2048 + co);
#pragma unroll
      for (int a = 0; a < 4; ++a)
#pragma unroll
        for (int b = 0; b < 2; ++b)
          acc[a][b] = __builtin_amdgcn_mfma_f32_16x16x32_bf16(af[a], bfr[b], acc[a][b], 0, 0, 0);
    }
  };

  stage(0, kb);
  stage(1, kb + 64);

  for (int ts = 0; ts < 6; ++ts) {
    WAITV(6);                         // stage ts landed; ts+1 stays in flight
    __builtin_amdgcn_s_barrier();
    __builtin_amdgcn_sched_barrier(0);
    compute(ts & 1);
    __builtin_amdgcn_s_barrier();     // all waves done reading buf ts&1
    __builtin_amdgcn_sched_barrier(0);
    stage(ts & 1, kb + (ts + 2) * 64);
    __builtin_amdgcn_sched_barrier(0);
  }
  WAITV(6);
  __builtin_amdgcn_s_barrier();
  __builtin_amdgcn_sched_barrier(0);
  compute(0);
  WAITV(0);
  __builtin_amdgcn_s_barrier();
  __builtin_amdgcn_sched_barrier(0);
  compute(1);

  // Epilogue: atomic-accumulate partial sums onto bias-pre-initialized out.
  int rmap[4][4];
  bool vld[4][4];
#pragma unroll
  for (int m = 0; m < 4; ++m) {
#pragma unroll
    for (int j = 0; j < 4; ++j) {
      const int lr = wr * 64 + m * 16 + (lane >> 4) * 4 + j;
      const bool v = (m0 + lr) < cnt_h;
      vld[m][j] = v;
      rmap[m][j] = v ? rows[basep + m0 + lr] : 0;
    }
  }
#pragma unroll
  for (int n = 0; n < 2; ++n) {
    const int c = n0 + wc * 32 + n * 16 + (lane & 15);
#pragma unroll
    for (int m = 0; m < 4; ++m) {
#pragma unroll
      for (int j = 0; j < 4; ++j) {
        if (vld[m][j])
          unsafeAtomicAdd(&out[(size_t)rmap[m][j] * 1024 + c], acc[m][n][j]);
      }
    }
  }
}

extern "C" void kernel_launch(void* const* d_in, const int* in_sizes, int n_in,
                              void* d_out, int out_size, void* d_ws, size_t ws_size,
                              hipStream_t stream) {
  const float* X = (const float*)d_in[0];
  const int* idx = (const int*)d_in[1];
  const float* W = (const float*)d_in[2];
  const float* bias = (const float*)d_in[3];
  float* out = (float*)d_out;

  char* ws = (char*)d_ws;
  int* cnt = (int*)ws;                                   // 8 ints @ 0
  int* base8 = (int*)(ws + 64);                          // 9 ints @ 64
  int* rows = (int*)(ws + 256);                          // 4160 ints
  unsigned short* Wt = (unsigned short*)(ws + 32768);    // 8*1024 rows * 2KB = 16 MB
  unsigned short* Ap = (unsigned short*)(ws + 32768 + 16777216);  // 4224 rows * 2KB

  k_prep<<<dim3(2049), 256, 0, stream>>>(W, idx, Wt, cnt, base8, rows);
  k_gather<<<dim3(4160), 256, 0, stream>>>(X, idx, rows, Ap, bias, out);
  // 8 heads (xcd-affine) x 16 n-tiles x 2 k-halves x 16 m-tiles
  k_gemm<<<dim3(8 * 16 * 2 * 16), 256, 0, stream>>>(Ap, Wt, rows, cnt, base8, out);
}